// Round 2
// baseline (389.810 us; speedup 1.0000x reference)
//
#include <hip/hip_runtime.h>

#define N_NODES 40000
#define N_EDGES 640000
#define DIM 128
#define NBLK_SCAN ((N_NODES + 255) / 256)   // 157

typedef __bf16 bf16;
typedef __bf16 v8bf __attribute__((ext_vector_type(8)));
typedef float f32x4 __attribute__((ext_vector_type(4)));

#define MFMA(a, b, c) __builtin_amdgcn_mfma_f32_16x16x32_bf16(a, b, c, 0, 0, 0)

// ---------------------------------------------------------------------------
// dtype helpers (F32: global floats are float32; else packed bf16)
// ---------------------------------------------------------------------------
template<bool F32>
__device__ __forceinline__ float ldf(const void* p, int i) {
    if constexpr (F32) return ((const float*)p)[i];
    else               return (float)((const bf16*)p)[i];
}

template<bool F32>
__device__ __forceinline__ void stf(void* p, size_t i, float v) {
    if constexpr (F32) ((float*)p)[i] = v;
    else               ((bf16*)p)[i] = (bf16)v;
}

template<bool I64>
__device__ __forceinline__ int ldi(const void* p, size_t i) {
    if constexpr (I64) return (int)((const long long*)p)[i];
    else               return ((const int*)p)[i];
}

// stage nElem contiguous floats (global) -> bf16 LDS
template<bool F32>
__device__ __forceinline__ void stage_vec(bf16* dst, const void* src, int nElem, int tid) {
    if constexpr (F32) {
        const float4* g = (const float4*)src;
        for (int i = tid; i < nElem / 4; i += 256) {
            float4 v = g[i];
            bf16* d = dst + i * 4;
            d[0] = (bf16)v.x; d[1] = (bf16)v.y; d[2] = (bf16)v.z; d[3] = (bf16)v.w;
        }
    } else {
        const uint4* g = (const uint4*)src;
        uint4* l = (uint4*)dst;
        for (int i = tid; i < nElem / 8; i += 256) l[i] = g[i];
    }
}

// stage a 128-row x 128-col tile starting at row0 (row-guarded) -> bf16 LDS
template<bool F32>
__device__ __forceinline__ void stage_tile(bf16* dst, const void* src, int row0, int tid) {
    if constexpr (F32) {
        const float4* g = (const float4*)src;   // row stride = 32 float4
        int r = tid >> 5, c = tid & 31;
        #pragma unroll
        for (int j = 0; j < 16; ++j) {
            int rr = r + 8 * j;
            float4 v = {0.f, 0.f, 0.f, 0.f};
            if (row0 + rr < N_NODES) v = g[(size_t)(row0 + rr) * 32 + c];
            bf16* d = dst + rr * DIM + c * 4;
            d[0] = (bf16)v.x; d[1] = (bf16)v.y; d[2] = (bf16)v.z; d[3] = (bf16)v.w;
        }
    } else {
        const uint4* g = (const uint4*)src;     // row stride = 16 uint4
        uint4* l = (uint4*)dst;
        int r = tid >> 4, c = tid & 15;
        #pragma unroll
        for (int j = 0; j < 8; ++j) {
            int rr = r + 16 * j;
            uint4 v = {0, 0, 0, 0};
            if (row0 + rr < N_NODES) v = g[(size_t)(row0 + rr) * 16 + c];
            l[rr * 16 + c] = v;
        }
    }
}

// stage a 128x128 bf16 tile (our own ws buffers, always bf16), row-guarded
__device__ __forceinline__ void stage_tile_bf16(bf16* dst, const bf16* src, int row0, int tid) {
    const uint4* g = (const uint4*)src;
    uint4* l = (uint4*)dst;
    int r = tid >> 4, c = tid & 15;
    #pragma unroll
    for (int j = 0; j < 8; ++j) {
        int rr = r + 16 * j;
        uint4 v = {0, 0, 0, 0};
        if (row0 + rr < N_NODES) v = g[(size_t)(row0 + rr) * 16 + c];
        l[rr * 16 + c] = v;
    }
}

// ---------------------------------------------------------------------------
// Mode detection: flags[0]=1 if floats are f32; flags[1]=1 if ints are int64.
// Discriminators: low halfwords of f32 words are random mantissa bits ->
// exponent-field >= 0xC0 appears w.p. 25%/sample; genuine bf16 data (|v|<16)
// never exceeds exp 0x82. int64 indices (<40000) have all-zero high words;
// int32 data puts a (nonzero w.h.p.) index in every "high word" slot.
// ---------------------------------------------------------------------------
__global__ __launch_bounds__(256) void detect_kernel(const unsigned short* __restrict__ xh,
                                                     const unsigned int* __restrict__ eiw,
                                                     int* __restrict__ flags) {
    __shared__ int sf[2];
    int tid = threadIdx.x;
    if (tid == 0) { sf[0] = 0; sf[1] = 0; }
    __syncthreads();
    int isf32 = 0; unsigned int orhi = 0;
    #pragma unroll
    for (int j = 0; j < 4; ++j) {
        unsigned short h = xh[2 * (tid + 256 * j)];     // low halfword of slot
        if (((h >> 7) & 0xFF) >= 0xC0) isf32 = 1;
        orhi |= eiw[2 * (tid + 256 * j) + 1];           // high word of slot
    }
    if (isf32) atomicOr(&sf[0], 1);
    if (orhi)  atomicOr(&sf[1], 1);
    __syncthreads();
    if (tid == 0) { flags[0] = sf[0]; flags[1] = sf[1] ? 0 : 1; }
}

// ---------------------------------------------------------------------------
// Message MLP per *node*: y = relu(x@W1^T+b1)@W2^T+b2   (E-fold cheaper than
// per-edge). MFMA 16x16x32 bf16; A[m=lane&15][k=quad*8+j]; B from W rows
// (K-contiguous); C/D col=lane&15,row=quad*4+reg.
// ---------------------------------------------------------------------------
template<bool F32>
__device__ void msg_body(const void* x, const void* W1, const void* b1,
                         const void* W2, const void* b2, bf16* __restrict__ y,
                         bf16* sW1, bf16* sW2, bf16* sT) {
    const int tid = threadIdx.x;
    const int row0 = blockIdx.x * DIM;

    stage_vec<F32>(sW1, W1, DIM * DIM, tid);
    stage_vec<F32>(sW2, W2, DIM * DIM, tid);
    stage_tile<F32>(sT, x, row0, tid);
    __syncthreads();

    const int lane = tid & 63, wave = tid >> 6;
    const int l15 = lane & 15, quad = lane >> 4;
    const int wb = wave * 32;

    f32x4 acc[2][8] = {};
    #pragma unroll
    for (int kt = 0; kt < 4; ++kt) {
        int k0 = kt * 32 + quad * 8;
        v8bf a0 = *(const v8bf*)&sT[(wb + l15) * DIM + k0];
        v8bf a1 = *(const v8bf*)&sT[(wb + 16 + l15) * DIM + k0];
        #pragma unroll
        for (int ct = 0; ct < 8; ++ct) {
            v8bf b = *(const v8bf*)&sW1[(ct * 16 + l15) * DIM + k0];
            acc[0][ct] = MFMA(a0, b, acc[0][ct]);
            acc[1][ct] = MFMA(a1, b, acc[1][ct]);
        }
    }
    __syncthreads();
    #pragma unroll
    for (int ct = 0; ct < 8; ++ct) {
        float bb = ldf<F32>(b1, ct * 16 + l15);
        #pragma unroll
        for (int i = 0; i < 2; ++i)
            #pragma unroll
            for (int r = 0; r < 4; ++r) {
                int row = wb + i * 16 + quad * 4 + r;
                sT[row * DIM + ct * 16 + l15] = (bf16)fmaxf(acc[i][ct][r] + bb, 0.f);
            }
    }
    __syncthreads();

    f32x4 acc2[2][8] = {};
    #pragma unroll
    for (int kt = 0; kt < 4; ++kt) {
        int k0 = kt * 32 + quad * 8;
        v8bf a0 = *(const v8bf*)&sT[(wb + l15) * DIM + k0];
        v8bf a1 = *(const v8bf*)&sT[(wb + 16 + l15) * DIM + k0];
        #pragma unroll
        for (int ct = 0; ct < 8; ++ct) {
            v8bf b = *(const v8bf*)&sW2[(ct * 16 + l15) * DIM + k0];
            acc2[0][ct] = MFMA(a0, b, acc2[0][ct]);
            acc2[1][ct] = MFMA(a1, b, acc2[1][ct]);
        }
    }
    #pragma unroll
    for (int ct = 0; ct < 8; ++ct) {
        float bb = ldf<F32>(b2, ct * 16 + l15);
        #pragma unroll
        for (int i = 0; i < 2; ++i)
            #pragma unroll
            for (int r = 0; r < 4; ++r) {
                int row = wb + i * 16 + quad * 4 + r;
                int grow = row0 + row;
                if (grow < N_NODES)
                    y[(size_t)grow * DIM + ct * 16 + l15] = (bf16)(acc2[i][ct][r] + bb);
            }
    }
}

__global__ __launch_bounds__(256) void msg_mlp_kernel(
    const void* x, const void* W1, const void* b1, const void* W2, const void* b2,
    bf16* y, const int* flags) {
    __shared__ __align__(16) bf16 sW1[DIM * DIM];
    __shared__ __align__(16) bf16 sW2[DIM * DIM];
    __shared__ __align__(16) bf16 sT[DIM * DIM];
    if (flags[0]) msg_body<true>(x, W1, b1, W2, b2, y, sW1, sW2, sT);
    else          msg_body<false>(x, W1, b1, W2, b2, y, sW1, sW2, sT);
}

// ---------------------------------------------------------------------------
// CSR build: histogram -> 2-level exclusive scan -> counting-sort scatter
// ---------------------------------------------------------------------------
template<bool I64>
__device__ void hist_body(const void* ei, int* deg) {
    int e = blockIdx.x * 256 + threadIdx.x;
    if (e < N_EDGES) atomicAdd(&deg[ldi<I64>(ei, (size_t)N_EDGES + e)], 1);
}
__global__ __launch_bounds__(256) void hist_kernel(const void* ei, int* deg, const int* flags) {
    if (flags[1]) hist_body<true>(ei, deg); else hist_body<false>(ei, deg);
}

__global__ __launch_bounds__(256) void scan1_kernel(const int* __restrict__ deg,
                                                    int* __restrict__ bscan,
                                                    int* __restrict__ bsum) {
    __shared__ int s[256];
    int tid = threadIdx.x;
    int i = blockIdx.x * 256 + tid;
    int v = (i < N_NODES) ? deg[i] : 0;
    s[tid] = v;
    for (int off = 1; off < 256; off <<= 1) {
        __syncthreads();
        int t = (tid >= off) ? s[tid - off] : 0;
        __syncthreads();
        s[tid] += t;
    }
    if (i < N_NODES) bscan[i] = s[tid] - v;
    if (tid == 255) bsum[blockIdx.x] = s[255];
}

__global__ __launch_bounds__(256) void scan2_kernel(int* __restrict__ bsum) {
    __shared__ int s[256];
    int tid = threadIdx.x;
    int v = (tid < NBLK_SCAN) ? bsum[tid] : 0;
    s[tid] = v;
    for (int off = 1; off < 256; off <<= 1) {
        __syncthreads();
        int t = (tid >= off) ? s[tid - off] : 0;
        __syncthreads();
        s[tid] += t;
    }
    if (tid < NBLK_SCAN) bsum[tid] = s[tid] - v;
}

__global__ __launch_bounds__(256) void scan3_kernel(const int* __restrict__ bscan,
                                                    const int* __restrict__ bsum,
                                                    int* __restrict__ offsets) {
    int i = blockIdx.x * 256 + threadIdx.x;
    if (i < N_NODES) offsets[i] = bscan[i] + bsum[blockIdx.x];
}

template<bool I64>
__device__ void scatter_body(const void* ei, int* offsets, int* srcs) {
    int e = blockIdx.x * 256 + threadIdx.x;
    if (e < N_EDGES) {
        int d = ldi<I64>(ei, (size_t)N_EDGES + e);
        int pos = atomicAdd(&offsets[d], 1);
        srcs[pos] = ldi<I64>(ei, e);
    }
}
__global__ __launch_bounds__(256) void scatter_kernel(const void* ei, int* offsets, int* srcs,
                                                      const int* flags) {
    if (flags[1]) scatter_body<true>(ei, offsets, srcs);
    else          scatter_body<false>(ei, offsets, srcs);
}

// ---------------------------------------------------------------------------
// Per-node gather-mean over CSR: agg[n] = mean y[srcs[beg..end)]
// ---------------------------------------------------------------------------
__global__ __launch_bounds__(256) void agg_kernel(const bf16* __restrict__ y,
                                                  const int* __restrict__ srcs,
                                                  const int* __restrict__ offsets,
                                                  const int* __restrict__ deg,
                                                  bf16* __restrict__ agg) {
    int node = blockIdx.x * 2 + (threadIdx.x >> 7);
    int d = threadIdx.x & 127;
    if (node >= N_NODES) return;
    int end = offsets[node];            // beg + cnt after scatter
    int cnt = deg[node];
    int beg = end - cnt;
    float s = 0.f;
    for (int e = beg; e < end; ++e)
        s += (float)y[(size_t)srcs[e] * DIM + d];
    float c = (float)(cnt > 0 ? cnt : 1);
    agg[(size_t)node * DIM + d] = (bf16)(s / c);
}

// ---------------------------------------------------------------------------
// Update MLP + residual + LayerNorm (fused epilogue, 16-lane shuffle reduce)
// ---------------------------------------------------------------------------
template<bool F32>
__device__ void update_body(const void* x, const bf16* __restrict__ agg,
                            const void* Wu1, const void* bu1, const void* Wu2, const void* bu2,
                            const void* gamma, const void* beta, void* out,
                            bf16* sX, bf16* sH, bf16* sW) {
    const int tid = threadIdx.x;
    const int row0 = blockIdx.x * DIM;

    stage_vec<F32>(sW, Wu1, DIM * 256, tid);        // Wu1: 128 x 256
    stage_tile<F32>(sX, x, row0, tid);
    stage_tile_bf16(sH, agg, row0, tid);
    __syncthreads();

    const int lane = tid & 63, wave = tid >> 6;
    const int l15 = lane & 15, quad = lane >> 4;
    const int wb = wave * 32;

    // layer 1: K = 256 over [x | agg]
    f32x4 acc[2][8] = {};
    #pragma unroll
    for (int kt = 0; kt < 8; ++kt) {
        int k0 = kt * 32 + quad * 8;
        const bf16* aT = (kt < 4) ? sX : sH;
        int ko = (kt < 4) ? k0 : (k0 - 128);
        v8bf a0 = *(const v8bf*)&aT[(wb + l15) * DIM + ko];
        v8bf a1 = *(const v8bf*)&aT[(wb + 16 + l15) * DIM + ko];
        #pragma unroll
        for (int ct = 0; ct < 8; ++ct) {
            v8bf b = *(const v8bf*)&sW[(ct * 16 + l15) * 256 + k0];
            acc[0][ct] = MFMA(a0, b, acc[0][ct]);
            acc[1][ct] = MFMA(a1, b, acc[1][ct]);
        }
    }
    __syncthreads();                    // done reading Wu1 & agg tile
    #pragma unroll
    for (int ct = 0; ct < 8; ++ct) {
        float bb = ldf<F32>(bu1, ct * 16 + l15);
        #pragma unroll
        for (int i = 0; i < 2; ++i)
            #pragma unroll
            for (int r = 0; r < 4; ++r) {
                int row = wb + i * 16 + quad * 4 + r;
                sH[row * DIM + ct * 16 + l15] = (bf16)fmaxf(acc[i][ct][r] + bb, 0.f);
            }
    }
    stage_vec<F32>(sW, Wu2, DIM * DIM, tid);        // Wu2 into first half of sW
    __syncthreads();

    // layer 2: K = 128
    f32x4 acc2[2][8] = {};
    #pragma unroll
    for (int kt = 0; kt < 4; ++kt) {
        int k0 = kt * 32 + quad * 8;
        v8bf a0 = *(const v8bf*)&sH[(wb + l15) * DIM + k0];
        v8bf a1 = *(const v8bf*)&sH[(wb + 16 + l15) * DIM + k0];
        #pragma unroll
        for (int ct = 0; ct < 8; ++ct) {
            v8bf b = *(const v8bf*)&sW[(ct * 16 + l15) * DIM + k0];
            acc2[0][ct] = MFMA(a0, b, acc2[0][ct]);
            acc2[1][ct] = MFMA(a1, b, acc2[1][ct]);
        }
    }

    // epilogue: +bu2, +x, LayerNorm, store
    float bu2c[8], gc[8], bc[8];
    #pragma unroll
    for (int ct = 0; ct < 8; ++ct) {
        int col = ct * 16 + l15;
        bu2c[ct] = ldf<F32>(bu2, col);
        gc[ct]   = ldf<F32>(gamma, col);
        bc[ct]   = ldf<F32>(beta, col);
    }
    #pragma unroll
    for (int i = 0; i < 2; ++i) {
        #pragma unroll
        for (int r = 0; r < 4; ++r) {
            int row = wb + i * 16 + quad * 4 + r;
            float u[8], s1 = 0.f, s2 = 0.f;
            #pragma unroll
            for (int ct = 0; ct < 8; ++ct) {
                float v = acc2[i][ct][r] + bu2c[ct] + (float)sX[row * DIM + ct * 16 + l15];
                u[ct] = v; s1 += v; s2 += v * v;
            }
            #pragma unroll
            for (int off = 1; off < 16; off <<= 1) {
                s1 += __shfl_xor(s1, off);
                s2 += __shfl_xor(s2, off);
            }
            float mean = s1 * (1.f / 128.f);
            float var  = s2 * (1.f / 128.f) - mean * mean;
            float rstd = rsqrtf(var + 1e-5f);
            int grow = row0 + row;
            if (grow < N_NODES) {
                #pragma unroll
                for (int ct = 0; ct < 8; ++ct)
                    stf<F32>(out, (size_t)grow * DIM + ct * 16 + l15,
                             (u[ct] - mean) * rstd * gc[ct] + bc[ct]);
            }
        }
    }
}

__global__ __launch_bounds__(256) void update_kernel(
    const void* x, const bf16* agg, const void* Wu1, const void* bu1,
    const void* Wu2, const void* bu2, const void* gamma, const void* beta,
    void* out, const int* flags) {
    __shared__ __align__(16) bf16 sX[DIM * DIM];    // 32 KB
    __shared__ __align__(16) bf16 sH[DIM * DIM];    // 32 KB
    __shared__ __align__(16) bf16 sW[DIM * 256];    // 64 KB
    if (flags[0]) update_body<true>(x, agg, Wu1, bu1, Wu2, bu2, gamma, beta, out, sX, sH, sW);
    else          update_body<false>(x, agg, Wu1, bu1, Wu2, bu2, gamma, beta, out, sX, sH, sW);
}

// ---------------------------------------------------------------------------
extern "C" void kernel_launch(void* const* d_in, const int* in_sizes, int n_in,
                              void* d_out, int out_size, void* d_ws, size_t ws_size,
                              hipStream_t stream) {
    const void* x   = d_in[0];
    const void* ei  = d_in[1];
    const void* Wm1 = d_in[2];
    const void* bm1 = d_in[3];
    const void* Wm2 = d_in[4];
    const void* bm2 = d_in[5];
    const void* Wu1 = d_in[6];
    const void* bu1 = d_in[7];
    const void* Wu2 = d_in[8];
    const void* bu2 = d_in[9];
    const void* gam = d_in[10];
    const void* bet = d_in[11];

    char* ws = (char*)d_ws;
    size_t off = 0;
    auto alloc = [&](size_t bytes) {
        void* p = ws + off;
        off += (bytes + 255) & ~(size_t)255;
        return p;
    };
    bf16* y       = (bf16*)alloc((size_t)N_NODES * DIM * sizeof(bf16));  // 10.24 MB
    bf16* agg     = (bf16*)alloc((size_t)N_NODES * DIM * sizeof(bf16));  // 10.24 MB
    int*  deg     = (int*)alloc(N_NODES * sizeof(int));
    int*  offsets = (int*)alloc(N_NODES * sizeof(int));
    int*  bscan   = (int*)alloc(N_NODES * sizeof(int));
    int*  bsum    = (int*)alloc(1024);
    int*  srcs    = (int*)alloc((size_t)N_EDGES * sizeof(int));          // 2.56 MB
    int*  flags   = (int*)alloc(256);

    hipMemsetAsync(deg, 0, N_NODES * sizeof(int), stream);

    detect_kernel<<<1, 256, 0, stream>>>((const unsigned short*)x, (const unsigned int*)ei, flags);
    msg_mlp_kernel<<<(N_NODES + 127) / 128, 256, 0, stream>>>(x, Wm1, bm1, Wm2, bm2, y, flags);
    hist_kernel<<<(N_EDGES + 255) / 256, 256, 0, stream>>>(ei, deg, flags);
    scan1_kernel<<<NBLK_SCAN, 256, 0, stream>>>(deg, bscan, bsum);
    scan2_kernel<<<1, 256, 0, stream>>>(bsum);
    scan3_kernel<<<NBLK_SCAN, 256, 0, stream>>>(bscan, bsum, offsets);
    scatter_kernel<<<(N_EDGES + 255) / 256, 256, 0, stream>>>(ei, offsets, srcs, flags);
    agg_kernel<<<N_NODES / 2, 256, 0, stream>>>(y, srcs, offsets, deg, agg);
    update_kernel<<<(N_NODES + 127) / 128, 256, 0, stream>>>(x, agg, Wu1, bu1, Wu2, bu2, gam, bet, d_out, flags);
}

// Round 3
// 297.954 us; speedup vs baseline: 1.3083x; 1.3083x over previous
//
#include <hip/hip_runtime.h>

#define N_NODES 40000
#define N_EDGES 640000
#define DIM 128
#define NBLK_SCAN ((N_NODES + 255) / 256)   // 157
#define NBLK_TILE ((N_NODES + 255) / 256)   // 157 (two 128-row tiles per block)

typedef __bf16 bf16;
typedef __bf16 v8bf __attribute__((ext_vector_type(8)));
typedef float f32x4 __attribute__((ext_vector_type(4)));

#define MFMA(a, b, c) __builtin_amdgcn_mfma_f32_16x16x32_bf16(a, b, c, 0, 0, 0)

// ---------------------------------------------------------------------------
// dtype helpers (F32: global floats are float32; else packed bf16)
// ---------------------------------------------------------------------------
template<bool F32>
__device__ __forceinline__ float ldf(const void* p, int i) {
    if constexpr (F32) return ((const float*)p)[i];
    else               return (float)((const bf16*)p)[i];
}

template<bool F32>
__device__ __forceinline__ void stf(void* p, size_t i, float v) {
    if constexpr (F32) ((float*)p)[i] = v;
    else               ((bf16*)p)[i] = (bf16)v;
}

template<bool I64>
__device__ __forceinline__ int ldi(const void* p, size_t i) {
    if constexpr (I64) return (int)((const long long*)p)[i];
    else               return ((const int*)p)[i];
}

// stage nElem contiguous floats (global) -> bf16 LDS
template<bool F32>
__device__ __forceinline__ void stage_vec(bf16* dst, const void* src, int nElem, int tid) {
    if constexpr (F32) {
        const float4* g = (const float4*)src;
        for (int i = tid; i < nElem / 4; i += 256) {
            float4 v = g[i];
            bf16* d = dst + i * 4;
            d[0] = (bf16)v.x; d[1] = (bf16)v.y; d[2] = (bf16)v.z; d[3] = (bf16)v.w;
        }
    } else {
        const uint4* g = (const uint4*)src;
        uint4* l = (uint4*)dst;
        for (int i = tid; i < nElem / 8; i += 256) l[i] = g[i];
    }
}

// stage a 128-row x 128-col tile starting at row0 (row-guarded) -> bf16 LDS
template<bool F32>
__device__ __forceinline__ void stage_tile(bf16* dst, const void* src, int row0, int tid) {
    if constexpr (F32) {
        const float4* g = (const float4*)src;   // row stride = 32 float4
        int r = tid >> 5, c = tid & 31;
        #pragma unroll
        for (int j = 0; j < 16; ++j) {
            int rr = r + 8 * j;
            float4 v = {0.f, 0.f, 0.f, 0.f};
            if (row0 + rr < N_NODES) v = g[(size_t)(row0 + rr) * 32 + c];
            bf16* d = dst + rr * DIM + c * 4;
            d[0] = (bf16)v.x; d[1] = (bf16)v.y; d[2] = (bf16)v.z; d[3] = (bf16)v.w;
        }
    } else {
        const uint4* g = (const uint4*)src;     // row stride = 16 uint4
        uint4* l = (uint4*)dst;
        int r = tid >> 4, c = tid & 15;
        #pragma unroll
        for (int j = 0; j < 8; ++j) {
            int rr = r + 16 * j;
            uint4 v = {0, 0, 0, 0};
            if (row0 + rr < N_NODES) v = g[(size_t)(row0 + rr) * 16 + c];
            l[rr * 16 + c] = v;
        }
    }
}

// stage a 128x128 bf16 tile (our own ws buffers, always bf16), row-guarded
__device__ __forceinline__ void stage_tile_bf16(bf16* dst, const bf16* src, int row0, int tid) {
    const uint4* g = (const uint4*)src;
    uint4* l = (uint4*)dst;
    int r = tid >> 4, c = tid & 15;
    #pragma unroll
    for (int j = 0; j < 8; ++j) {
        int rr = r + 16 * j;
        uint4 v = {0, 0, 0, 0};
        if (row0 + rr < N_NODES) v = g[(size_t)(row0 + rr) * 16 + c];
        l[rr * 16 + c] = v;
    }
}

// ---------------------------------------------------------------------------
// Mode detection: flags[0]=1 if floats are f32; flags[1]=1 if ints are int64.
// ---------------------------------------------------------------------------
__global__ __launch_bounds__(256) void detect_kernel(const unsigned short* __restrict__ xh,
                                                     const unsigned int* __restrict__ eiw,
                                                     int* __restrict__ flags) {
    __shared__ int sf[2];
    int tid = threadIdx.x;
    if (tid == 0) { sf[0] = 0; sf[1] = 0; }
    __syncthreads();
    int isf32 = 0; unsigned int orhi = 0;
    #pragma unroll
    for (int j = 0; j < 4; ++j) {
        unsigned short h = xh[2 * (tid + 256 * j)];     // low halfword of slot
        if (((h >> 7) & 0xFF) >= 0xC0) isf32 = 1;
        orhi |= eiw[2 * (tid + 256 * j) + 1];           // high word of slot
    }
    if (isf32) atomicOr(&sf[0], 1);
    if (orhi)  atomicOr(&sf[1], 1);
    __syncthreads();
    if (tid == 0) { flags[0] = sf[0]; flags[1] = sf[1] ? 0 : 1; }
}

// ---------------------------------------------------------------------------
// Message MLP per *node*: y = relu(x@W1^T+b1)@W2^T+b2. Two 128-row tiles per
// block; weights staged once. MFMA 16x16x32 bf16.
// ---------------------------------------------------------------------------
template<bool F32>
__device__ void msg_body(const void* x, const void* W1, const void* b1,
                         const void* W2, const void* b2, bf16* __restrict__ y,
                         bf16* sW1, bf16* sW2, bf16* sT) {
    const int tid = threadIdx.x;
    stage_vec<F32>(sW1, W1, DIM * DIM, tid);
    stage_vec<F32>(sW2, W2, DIM * DIM, tid);

    const int lane = tid & 63, wave = tid >> 6;
    const int l15 = lane & 15, quad = lane >> 4;
    const int wb = wave * 32;

    for (int t = 0; t < 2; ++t) {
        const int row0 = blockIdx.x * 256 + t * 128;
        __syncthreads();                     // prev-tile readers done / weights staged
        stage_tile<F32>(sT, x, row0, tid);
        __syncthreads();

        f32x4 acc[2][8] = {};
        #pragma unroll
        for (int kt = 0; kt < 4; ++kt) {
            int k0 = kt * 32 + quad * 8;
            v8bf a0 = *(const v8bf*)&sT[(wb + l15) * DIM + k0];
            v8bf a1 = *(const v8bf*)&sT[(wb + 16 + l15) * DIM + k0];
            #pragma unroll
            for (int ct = 0; ct < 8; ++ct) {
                v8bf b = *(const v8bf*)&sW1[(ct * 16 + l15) * DIM + k0];
                acc[0][ct] = MFMA(a0, b, acc[0][ct]);
                acc[1][ct] = MFMA(a1, b, acc[1][ct]);
            }
        }
        __syncthreads();
        #pragma unroll
        for (int ct = 0; ct < 8; ++ct) {
            float bb = ldf<F32>(b1, ct * 16 + l15);
            #pragma unroll
            for (int i = 0; i < 2; ++i)
                #pragma unroll
                for (int r = 0; r < 4; ++r) {
                    int row = wb + i * 16 + quad * 4 + r;
                    sT[row * DIM + ct * 16 + l15] = (bf16)fmaxf(acc[i][ct][r] + bb, 0.f);
                }
        }
        __syncthreads();

        f32x4 acc2[2][8] = {};
        #pragma unroll
        for (int kt = 0; kt < 4; ++kt) {
            int k0 = kt * 32 + quad * 8;
            v8bf a0 = *(const v8bf*)&sT[(wb + l15) * DIM + k0];
            v8bf a1 = *(const v8bf*)&sT[(wb + 16 + l15) * DIM + k0];
            #pragma unroll
            for (int ct = 0; ct < 8; ++ct) {
                v8bf b = *(const v8bf*)&sW2[(ct * 16 + l15) * DIM + k0];
                acc2[0][ct] = MFMA(a0, b, acc2[0][ct]);
                acc2[1][ct] = MFMA(a1, b, acc2[1][ct]);
            }
        }
        #pragma unroll
        for (int ct = 0; ct < 8; ++ct) {
            float bb = ldf<F32>(b2, ct * 16 + l15);
            #pragma unroll
            for (int i = 0; i < 2; ++i)
                #pragma unroll
                for (int r = 0; r < 4; ++r) {
                    int row = wb + i * 16 + quad * 4 + r;
                    int grow = row0 + row;
                    if (grow < N_NODES)
                        y[(size_t)grow * DIM + ct * 16 + l15] = (bf16)(acc2[i][ct][r] + bb);
                }
        }
    }
}

__global__ __launch_bounds__(256) void msg_mlp_kernel(
    const void* x, const void* W1, const void* b1, const void* W2, const void* b2,
    bf16* y, const int* flags) {
    __shared__ __align__(16) bf16 sW1[DIM * DIM];
    __shared__ __align__(16) bf16 sW2[DIM * DIM];
    __shared__ __align__(16) bf16 sT[DIM * DIM];
    if (flags[0]) msg_body<true>(x, W1, b1, W2, b2, y, sW1, sW2, sT);
    else          msg_body<false>(x, W1, b1, W2, b2, y, sW1, sW2, sT);
}

// ---------------------------------------------------------------------------
// CSR build: histogram -> 2-level exclusive scan -> counting-sort scatter
// ---------------------------------------------------------------------------
template<bool I64>
__device__ void hist_body(const void* ei, int* deg) {
    int e = blockIdx.x * 256 + threadIdx.x;
    if (e < N_EDGES) atomicAdd(&deg[ldi<I64>(ei, (size_t)N_EDGES + e)], 1);
}
__global__ __launch_bounds__(256) void hist_kernel(const void* ei, int* deg, const int* flags) {
    if (flags[1]) hist_body<true>(ei, deg); else hist_body<false>(ei, deg);
}

__global__ __launch_bounds__(256) void scan1_kernel(const int* __restrict__ deg,
                                                    int* __restrict__ bscan,
                                                    int* __restrict__ bsum) {
    __shared__ int s[256];
    int tid = threadIdx.x;
    int i = blockIdx.x * 256 + tid;
    int v = (i < N_NODES) ? deg[i] : 0;
    s[tid] = v;
    for (int off = 1; off < 256; off <<= 1) {
        __syncthreads();
        int t = (tid >= off) ? s[tid - off] : 0;
        __syncthreads();
        s[tid] += t;
    }
    if (i < N_NODES) bscan[i] = s[tid] - v;
    if (tid == 255) bsum[blockIdx.x] = s[255];
}

__global__ __launch_bounds__(256) void scan2_kernel(int* __restrict__ bsum) {
    __shared__ int s[256];
    int tid = threadIdx.x;
    int v = (tid < NBLK_SCAN) ? bsum[tid] : 0;
    s[tid] = v;
    for (int off = 1; off < 256; off <<= 1) {
        __syncthreads();
        int t = (tid >= off) ? s[tid - off] : 0;
        __syncthreads();
        s[tid] += t;
    }
    if (tid < NBLK_SCAN) bsum[tid] = s[tid] - v;
}

__global__ __launch_bounds__(256) void scan3_kernel(const int* __restrict__ bscan,
                                                    const int* __restrict__ bsum,
                                                    int* __restrict__ offsets) {
    int i = blockIdx.x * 256 + threadIdx.x;
    if (i < N_NODES) offsets[i] = bscan[i] + bsum[blockIdx.x];
}

template<bool I64>
__device__ void scatter_body(const void* ei, int* offsets, int* srcs) {
    int e = blockIdx.x * 256 + threadIdx.x;
    if (e < N_EDGES) {
        int d = ldi<I64>(ei, (size_t)N_EDGES + e);
        int pos = atomicAdd(&offsets[d], 1);
        srcs[pos] = ldi<I64>(ei, e);
    }
}
__global__ __launch_bounds__(256) void scatter_kernel(const void* ei, int* offsets, int* srcs,
                                                      const int* flags) {
    if (flags[1]) scatter_body<true>(ei, offsets, srcs);
    else          scatter_body<false>(ei, offsets, srcs);
}

// ---------------------------------------------------------------------------
// Per-node gather-mean, wave-per-node. Lane = (slot in [0,4), c16 in [0,16)).
// Each lane loads uint4 (8 bf16); 4 edges in flight per iter, dual-stream
// unroll -> 8. Cross-slot reduce: 2x shfl_xor. Lanes slot==0 write the row.
// ---------------------------------------------------------------------------
__device__ __forceinline__ void accum8(float* s, uint4 v) {
    v8bf b = __builtin_bit_cast(v8bf, v);
    #pragma unroll
    for (int j = 0; j < 8; ++j) s[j] += (float)b[j];
}

__global__ __launch_bounds__(256) void agg_kernel(const bf16* __restrict__ y,
                                                  const int* __restrict__ srcs,
                                                  const int* __restrict__ offsets,
                                                  const int* __restrict__ deg,
                                                  bf16* __restrict__ agg) {
    const int node = (blockIdx.x << 2) + (threadIdx.x >> 6);   // 4 waves/block, grid*4 == N_NODES
    const int lane = threadIdx.x & 63;
    const int slot = lane >> 4, c16 = lane & 15;
    const int end = offsets[node];          // beg + cnt after scatter
    const int cnt = deg[node];
    const int beg = end - cnt;
    const uint4* yv = (const uint4*)y;

    float s0[8] = {}, s1[8] = {};
    int e = beg + slot;
    for (; e + 4 < end; e += 8) {           // dual stream: e and e+4 both valid
        int i0 = srcs[e], i1 = srcs[e + 4];
        uint4 v0 = yv[(size_t)i0 * 16 + c16];
        uint4 v1 = yv[(size_t)i1 * 16 + c16];
        accum8(s0, v0);
        accum8(s1, v1);
    }
    if (e < end) {
        int i0 = srcs[e];
        accum8(s0, yv[(size_t)i0 * 16 + c16]);
    }
    float inv = 1.f / (float)(cnt > 0 ? cnt : 1);
    v8bf o;
    #pragma unroll
    for (int j = 0; j < 8; ++j) {
        float v = s0[j] + s1[j];
        v += __shfl_xor(v, 16);
        v += __shfl_xor(v, 32);
        o[j] = (bf16)(v * inv);
    }
    if (slot == 0)
        ((uint4*)agg)[(size_t)node * 16 + c16] = __builtin_bit_cast(uint4, o);
}

// ---------------------------------------------------------------------------
// Update MLP + residual + LayerNorm, two 128-row tiles per block.
// ---------------------------------------------------------------------------
template<bool F32>
__device__ void update_body(const void* x, const bf16* __restrict__ agg,
                            const void* Wu1, const void* bu1, const void* Wu2, const void* bu2,
                            const void* gamma, const void* beta, void* out,
                            bf16* sX, bf16* sH, bf16* sW) {
    const int tid = threadIdx.x;
    const int lane = tid & 63, wave = tid >> 6;
    const int l15 = lane & 15, quad = lane >> 4;
    const int wb = wave * 32;

    float bu2c[8], gc[8], bc[8];
    #pragma unroll
    for (int ct = 0; ct < 8; ++ct) {
        int col = ct * 16 + l15;
        bu2c[ct] = ldf<F32>(bu2, col);
        gc[ct]   = ldf<F32>(gamma, col);
        bc[ct]   = ldf<F32>(beta, col);
    }

    for (int t = 0; t < 2; ++t) {
        const int row0 = blockIdx.x * 256 + t * 128;
        __syncthreads();                        // prev-tile epilogue readers done
        stage_vec<F32>(sW, Wu1, DIM * 256, tid);   // Wu1 (Wu2 overwrote it last tile)
        stage_tile<F32>(sX, x, row0, tid);
        stage_tile_bf16(sH, agg, row0, tid);
        __syncthreads();

        // layer 1: K = 256 over [x | agg]
        f32x4 acc[2][8] = {};
        #pragma unroll
        for (int kt = 0; kt < 8; ++kt) {
            int k0 = kt * 32 + quad * 8;
            const bf16* aT = (kt < 4) ? sX : sH;
            int ko = (kt < 4) ? k0 : (k0 - 128);
            v8bf a0 = *(const v8bf*)&aT[(wb + l15) * DIM + ko];
            v8bf a1 = *(const v8bf*)&aT[(wb + 16 + l15) * DIM + ko];
            #pragma unroll
            for (int ct = 0; ct < 8; ++ct) {
                v8bf b = *(const v8bf*)&sW[(ct * 16 + l15) * 256 + k0];
                acc[0][ct] = MFMA(a0, b, acc[0][ct]);
                acc[1][ct] = MFMA(a1, b, acc[1][ct]);
            }
        }
        __syncthreads();                        // done reading Wu1 & agg tile
        #pragma unroll
        for (int ct = 0; ct < 8; ++ct) {
            float bb = ldf<F32>(bu1, ct * 16 + l15);
            #pragma unroll
            for (int i = 0; i < 2; ++i)
                #pragma unroll
                for (int r = 0; r < 4; ++r) {
                    int row = wb + i * 16 + quad * 4 + r;
                    sH[row * DIM + ct * 16 + l15] = (bf16)fmaxf(acc[i][ct][r] + bb, 0.f);
                }
        }
        stage_vec<F32>(sW, Wu2, DIM * DIM, tid);   // Wu2 into first half of sW
        __syncthreads();

        // layer 2: K = 128
        f32x4 acc2[2][8] = {};
        #pragma unroll
        for (int kt = 0; kt < 4; ++kt) {
            int k0 = kt * 32 + quad * 8;
            v8bf a0 = *(const v8bf*)&sH[(wb + l15) * DIM + k0];
            v8bf a1 = *(const v8bf*)&sH[(wb + 16 + l15) * DIM + k0];
            #pragma unroll
            for (int ct = 0; ct < 8; ++ct) {
                v8bf b = *(const v8bf*)&sW[(ct * 16 + l15) * DIM + k0];
                acc2[0][ct] = MFMA(a0, b, acc2[0][ct]);
                acc2[1][ct] = MFMA(a1, b, acc2[1][ct]);
            }
        }

        // epilogue: +bu2, +x residual, LayerNorm, store
        #pragma unroll
        for (int i = 0; i < 2; ++i) {
            #pragma unroll
            for (int r = 0; r < 4; ++r) {
                int row = wb + i * 16 + quad * 4 + r;
                float u[8], s1 = 0.f, s2 = 0.f;
                #pragma unroll
                for (int ct = 0; ct < 8; ++ct) {
                    float v = acc2[i][ct][r] + bu2c[ct] + (float)sX[row * DIM + ct * 16 + l15];
                    u[ct] = v; s1 += v; s2 += v * v;
                }
                #pragma unroll
                for (int off = 1; off < 16; off <<= 1) {
                    s1 += __shfl_xor(s1, off);
                    s2 += __shfl_xor(s2, off);
                }
                float mean = s1 * (1.f / 128.f);
                float var  = s2 * (1.f / 128.f) - mean * mean;
                float rstd = rsqrtf(var + 1e-5f);
                int grow = row0 + row;
                if (grow < N_NODES) {
                    #pragma unroll
                    for (int ct = 0; ct < 8; ++ct)
                        stf<F32>(out, (size_t)grow * DIM + ct * 16 + l15,
                                 (u[ct] - mean) * rstd * gc[ct] + bc[ct]);
                }
            }
        }
    }
}

__global__ __launch_bounds__(256) void update_kernel(
    const void* x, const bf16* agg, const void* Wu1, const void* bu1,
    const void* Wu2, const void* bu2, const void* gamma, const void* beta,
    void* out, const int* flags) {
    __shared__ __align__(16) bf16 sX[DIM * DIM];    // 32 KB
    __shared__ __align__(16) bf16 sH[DIM * DIM];    // 32 KB
    __shared__ __align__(16) bf16 sW[DIM * 256];    // 64 KB
    if (flags[0]) update_body<true>(x, agg, Wu1, bu1, Wu2, bu2, gamma, beta, out, sX, sH, sW);
    else          update_body<false>(x, agg, Wu1, bu1, Wu2, bu2, gamma, beta, out, sX, sH, sW);
}

// ---------------------------------------------------------------------------
extern "C" void kernel_launch(void* const* d_in, const int* in_sizes, int n_in,
                              void* d_out, int out_size, void* d_ws, size_t ws_size,
                              hipStream_t stream) {
    const void* x   = d_in[0];
    const void* ei  = d_in[1];
    const void* Wm1 = d_in[2];
    const void* bm1 = d_in[3];
    const void* Wm2 = d_in[4];
    const void* bm2 = d_in[5];
    const void* Wu1 = d_in[6];
    const void* bu1 = d_in[7];
    const void* Wu2 = d_in[8];
    const void* bu2 = d_in[9];
    const void* gam = d_in[10];
    const void* bet = d_in[11];

    char* ws = (char*)d_ws;
    size_t off = 0;
    auto alloc = [&](size_t bytes) {
        void* p = ws + off;
        off += (bytes + 255) & ~(size_t)255;
        return p;
    };
    bf16* y       = (bf16*)alloc((size_t)N_NODES * DIM * sizeof(bf16));  // 10.24 MB
    bf16* agg     = (bf16*)alloc((size_t)N_NODES * DIM * sizeof(bf16));  // 10.24 MB
    int*  deg     = (int*)alloc(N_NODES * sizeof(int));
    int*  offsets = (int*)alloc(N_NODES * sizeof(int));
    int*  bscan   = (int*)alloc(N_NODES * sizeof(int));
    int*  bsum    = (int*)alloc(1024);
    int*  srcs    = (int*)alloc((size_t)N_EDGES * sizeof(int));          // 2.56 MB
    int*  flags   = (int*)alloc(256);

    hipMemsetAsync(deg, 0, N_NODES * sizeof(int), stream);

    detect_kernel<<<1, 256, 0, stream>>>((const unsigned short*)x, (const unsigned int*)ei, flags);
    msg_mlp_kernel<<<NBLK_TILE, 256, 0, stream>>>(x, Wm1, bm1, Wm2, bm2, y, flags);
    hist_kernel<<<(N_EDGES + 255) / 256, 256, 0, stream>>>(ei, deg, flags);
    scan1_kernel<<<NBLK_SCAN, 256, 0, stream>>>(deg, bscan, bsum);
    scan2_kernel<<<1, 256, 0, stream>>>(bsum);
    scan3_kernel<<<NBLK_SCAN, 256, 0, stream>>>(bscan, bsum, offsets);
    scatter_kernel<<<(N_EDGES + 255) / 256, 256, 0, stream>>>(ei, offsets, srcs, flags);
    agg_kernel<<<N_NODES / 4, 256, 0, stream>>>(y, srcs, offsets, deg, agg);
    update_kernel<<<NBLK_TILE, 256, 0, stream>>>(x, agg, Wu1, bu1, Wu2, bu2, gam, bet, d_out, flags);
}

// Round 4
// 250.109 us; speedup vs baseline: 1.5586x; 1.1913x over previous
//
#include <hip/hip_runtime.h>

#define N_NODES 40000
#define N_EDGES 640000
#define DIM 128
#define NBLK_SCAN 157
#define NBLK_GEMM 313   // ceil(40000 / 128); 4 waves/block, 32 rows/wave

typedef __bf16 bf16;
typedef __bf16 v8bf __attribute__((ext_vector_type(8)));
typedef __bf16 v4bf __attribute__((ext_vector_type(4)));
typedef float f32x4 __attribute__((ext_vector_type(4)));

#define MFMA(a, b, c) __builtin_amdgcn_mfma_f32_16x16x32_bf16(a, b, c, 0, 0, 0)

// bf16 parameter pack offsets (elements)
#define OFF_WM1 0
#define OFF_BM1 16384
#define OFF_WM2 16512
#define OFF_BM2 32896
#define OFF_WU1 33024
#define OFF_BU1 65792
#define OFF_WU2 65920
#define OFF_BU2 82304
#define OFF_GAM 82432
#define OFF_BET 82560
#define NPARAM  82688

template<bool I64>
__device__ __forceinline__ int ldi(const void* p, size_t i) {
    if constexpr (I64) return (int)((const long long*)p)[i];
    else               return ((const int*)p)[i];
}

// ---------------------------------------------------------------------------
// Mode detection: flags[0]=1 if floats are f32; flags[1]=1 if ints are int64.
// f32 low halfwords are random mantissa bits (exp-field >= 0xC0 w.p. 25%);
// bf16 activations (|v|<16) never reach exp 0x83. int64 indices < 40000 have
// all-zero high words.
// ---------------------------------------------------------------------------
__global__ __launch_bounds__(256) void detect_kernel(const unsigned short* __restrict__ xh,
                                                     const unsigned int* __restrict__ eiw,
                                                     int* __restrict__ flags) {
    __shared__ int sf[2];
    int tid = threadIdx.x;
    if (tid == 0) { sf[0] = 0; sf[1] = 0; }
    __syncthreads();
    int isf32 = 0; unsigned int orhi = 0;
    #pragma unroll
    for (int j = 0; j < 4; ++j) {
        unsigned short h = xh[2 * (tid + 256 * j)];
        if (((h >> 7) & 0xFF) >= 0xC0) isf32 = 1;
        orhi |= eiw[2 * (tid + 256 * j) + 1];
    }
    if (isf32) atomicOr(&sf[0], 1);
    if (orhi)  atomicOr(&sf[1], 1);
    __syncthreads();
    if (tid == 0) { flags[0] = sf[0]; flags[1] = sf[1] ? 0 : 1; }
}

// ---------------------------------------------------------------------------
// Convert all weights/biases/gamma/beta into one bf16 pack (wp).
// ---------------------------------------------------------------------------
__global__ __launch_bounds__(256) void convert_params_kernel(
    const void* Wm1, const void* bm1, const void* Wm2, const void* bm2,
    const void* Wu1, const void* bu1, const void* Wu2, const void* bu2,
    const void* gam, const void* bet, const int* __restrict__ flags,
    bf16* __restrict__ wp)
{
    int i = blockIdx.x * 256 + threadIdx.x;
    if (i >= NPARAM) return;
    const void* src; int base;
    if      (i < OFF_BM1) { src = Wm1; base = OFF_WM1; }
    else if (i < OFF_WM2) { src = bm1; base = OFF_BM1; }
    else if (i < OFF_BM2) { src = Wm2; base = OFF_WM2; }
    else if (i < OFF_WU1) { src = bm2; base = OFF_BM2; }
    else if (i < OFF_BU1) { src = Wu1; base = OFF_WU1; }
    else if (i < OFF_WU2) { src = bu1; base = OFF_BU1; }
    else if (i < OFF_BU2) { src = Wu2; base = OFF_WU2; }
    else if (i < OFF_GAM) { src = bu2; base = OFF_BU2; }
    else if (i < OFF_BET) { src = gam; base = OFF_GAM; }
    else                  { src = bet; base = OFF_BET; }
    int j = i - base;
    float v = flags[0] ? ((const float*)src)[j] : (float)((const bf16*)src)[j];
    wp[i] = (bf16)v;
}

// ---------------------------------------------------------------------------
// Convert x -> bf16 (or straight copy if already bf16).
// ---------------------------------------------------------------------------
__global__ __launch_bounds__(256) void convert_x_kernel(const void* __restrict__ x,
                                                        const int* __restrict__ flags,
                                                        bf16* __restrict__ xb) {
    const int NT = N_NODES * DIM;
    int stride = gridDim.x * 256;
    if (flags[0]) {
        const float4* g = (const float4*)x;
        v4bf* o = (v4bf*)xb;
        for (int i = blockIdx.x * 256 + threadIdx.x; i < NT / 4; i += stride) {
            float4 v = g[i];
            v4bf t; t[0] = (bf16)v.x; t[1] = (bf16)v.y; t[2] = (bf16)v.z; t[3] = (bf16)v.w;
            o[i] = t;
        }
    } else {
        const uint4* g = (const uint4*)x;
        uint4* o = (uint4*)xb;
        for (int i = blockIdx.x * 256 + threadIdx.x; i < NT / 8; i += stride) o[i] = g[i];
    }
}

// ---------------------------------------------------------------------------
// Per-wave LDS-free GEMM helpers. Wave handles 32 rows x 128 cols.
// A-frag: A[m=lane&15][k=quad*8+j] read straight from global bf16 rows.
// B-frag: W row (ct*16+l15), cols k0..k0+8 (K-contiguous row-major weights).
// C/D: col=lane&15, row=quad*4+reg (+16*i).
// h1 transpose goes through 8 KB/wave XOR-swizzled scratch:
//   off(row,col) = row*128 + (((col>>3) ^ (row&15))<<3) + (col&7)
// -> b128 reads & b16 writes land 2-4-way max (2-way is free).
// ---------------------------------------------------------------------------

// msg: y = relu(x@W1^T+b1)@W2^T+b2, per node
__global__ __launch_bounds__(256) void msg_kernel(const bf16* __restrict__ xb,
                                                  const bf16* __restrict__ wp,
                                                  bf16* __restrict__ y)
{
    __shared__ __align__(16) bf16 sc[4][32 * DIM];   // 32 KB
    const int wave = threadIdx.x >> 6, lane = threadIdx.x & 63;
    const int l15 = lane & 15, quad = lane >> 4;
    const int row0 = (blockIdx.x * 4 + wave) * 32;
    bf16* s = sc[wave];
    const bf16* W1 = wp + OFF_WM1;
    const bf16* W2 = wp + OFF_WM2;

    const int ra = min(row0 + l15, N_NODES - 1);
    const int rb = min(row0 + 16 + l15, N_NODES - 1);

    // layer 1
    f32x4 acc[2][8] = {};
    #pragma unroll
    for (int kt = 0; kt < 4; ++kt) {
        int k0 = kt * 32 + quad * 8;
        v8bf a0 = *(const v8bf*)&xb[(size_t)ra * DIM + k0];
        v8bf a1 = *(const v8bf*)&xb[(size_t)rb * DIM + k0];
        #pragma unroll
        for (int ct = 0; ct < 8; ++ct) {
            v8bf b = *(const v8bf*)&W1[(ct * 16 + l15) * DIM + k0];
            acc[0][ct] = MFMA(a0, b, acc[0][ct]);
            acc[1][ct] = MFMA(a1, b, acc[1][ct]);
        }
    }
    // relu + bias -> swizzled scratch (wave-local; no barrier)
    #pragma unroll
    for (int ct = 0; ct < 8; ++ct) {
        float bb = (float)wp[OFF_BM1 + ct * 16 + l15];
        int c8w = (ct << 1) | (l15 >> 3);
        #pragma unroll
        for (int i = 0; i < 2; ++i)
            #pragma unroll
            for (int r = 0; r < 4; ++r) {
                int row = i * 16 + quad * 4 + r;
                s[row * DIM + (((c8w ^ (row & 15)) << 3) | (l15 & 7))] =
                    (bf16)fmaxf(acc[i][ct][r] + bb, 0.f);
            }
    }
    // layer 2
    f32x4 acc2[2][8] = {};
    #pragma unroll
    for (int kt = 0; kt < 4; ++kt) {
        int k0 = kt * 32 + quad * 8;
        int c8 = kt * 4 + quad;
        v8bf a0 = *(const v8bf*)&s[l15 * DIM + ((c8 ^ l15) << 3)];
        v8bf a1 = *(const v8bf*)&s[(16 + l15) * DIM + ((c8 ^ l15) << 3)];
        #pragma unroll
        for (int ct = 0; ct < 8; ++ct) {
            v8bf b = *(const v8bf*)&W2[(ct * 16 + l15) * DIM + k0];
            acc2[0][ct] = MFMA(a0, b, acc2[0][ct]);
            acc2[1][ct] = MFMA(a1, b, acc2[1][ct]);
        }
    }
    #pragma unroll
    for (int ct = 0; ct < 8; ++ct) {
        float bb = (float)wp[OFF_BM2 + ct * 16 + l15];
        #pragma unroll
        for (int i = 0; i < 2; ++i)
            #pragma unroll
            for (int r = 0; r < 4; ++r) {
                int grow = row0 + i * 16 + quad * 4 + r;
                if (grow < N_NODES)
                    y[(size_t)grow * DIM + ct * 16 + l15] = (bf16)(acc2[i][ct][r] + bb);
            }
    }
}

// update: u = relu([x|agg]@Wu1^T+bu1)@Wu2^T+bu2; h=u+x; LN(h)*gamma+beta
__global__ __launch_bounds__(256) void update_kernel(const bf16* __restrict__ xb,
                                                     const bf16* __restrict__ agg,
                                                     const bf16* __restrict__ wp,
                                                     const int* __restrict__ flags,
                                                     void* __restrict__ out)
{
    __shared__ __align__(16) bf16 sc[4][32 * DIM];   // 32 KB
    const int wave = threadIdx.x >> 6, lane = threadIdx.x & 63;
    const int l15 = lane & 15, quad = lane >> 4;
    const int row0 = (blockIdx.x * 4 + wave) * 32;
    bf16* s = sc[wave];
    const bf16* W1 = wp + OFF_WU1;   // 128 x 256
    const bf16* W2 = wp + OFF_WU2;
    const int of32 = flags[0];

    const int ra = min(row0 + l15, N_NODES - 1);
    const int rb = min(row0 + 16 + l15, N_NODES - 1);

    // layer 1: K = 256 over [x | agg]
    f32x4 acc[2][8] = {};
    #pragma unroll
    for (int kt = 0; kt < 8; ++kt) {
        int k0 = kt * 32 + quad * 8;
        const bf16* A = (kt < 4) ? xb : agg;
        int ko = (kt < 4) ? k0 : (k0 - 128);
        v8bf a0 = *(const v8bf*)&A[(size_t)ra * DIM + ko];
        v8bf a1 = *(const v8bf*)&A[(size_t)rb * DIM + ko];
        #pragma unroll
        for (int ct = 0; ct < 8; ++ct) {
            v8bf b = *(const v8bf*)&W1[(ct * 16 + l15) * 256 + k0];
            acc[0][ct] = MFMA(a0, b, acc[0][ct]);
            acc[1][ct] = MFMA(a1, b, acc[1][ct]);
        }
    }
    #pragma unroll
    for (int ct = 0; ct < 8; ++ct) {
        float bb = (float)wp[OFF_BU1 + ct * 16 + l15];
        int c8w = (ct << 1) | (l15 >> 3);
        #pragma unroll
        for (int i = 0; i < 2; ++i)
            #pragma unroll
            for (int r = 0; r < 4; ++r) {
                int row = i * 16 + quad * 4 + r;
                s[row * DIM + (((c8w ^ (row & 15)) << 3) | (l15 & 7))] =
                    (bf16)fmaxf(acc[i][ct][r] + bb, 0.f);
            }
    }
    // layer 2: K = 128
    f32x4 acc2[2][8] = {};
    #pragma unroll
    for (int kt = 0; kt < 4; ++kt) {
        int k0 = kt * 32 + quad * 8;
        int c8 = kt * 4 + quad;
        v8bf a0 = *(const v8bf*)&s[l15 * DIM + ((c8 ^ l15) << 3)];
        v8bf a1 = *(const v8bf*)&s[(16 + l15) * DIM + ((c8 ^ l15) << 3)];
        #pragma unroll
        for (int ct = 0; ct < 8; ++ct) {
            v8bf b = *(const v8bf*)&W2[(ct * 16 + l15) * DIM + k0];
            acc2[0][ct] = MFMA(a0, b, acc2[0][ct]);
            acc2[1][ct] = MFMA(a1, b, acc2[1][ct]);
        }
    }

    // epilogue: +bu2, +x residual, LayerNorm (16-lane quad reduce), store
    float bu2c[8], gc[8], bc[8];
    #pragma unroll
    for (int ct = 0; ct < 8; ++ct) {
        int col = ct * 16 + l15;
        bu2c[ct] = (float)wp[OFF_BU2 + col];
        gc[ct]   = (float)wp[OFF_GAM + col];
        bc[ct]   = (float)wp[OFF_BET + col];
    }
    #pragma unroll
    for (int i = 0; i < 2; ++i) {
        #pragma unroll
        for (int r = 0; r < 4; ++r) {
            int grow = row0 + i * 16 + quad * 4 + r;
            int growc = min(grow, N_NODES - 1);
            float u[8], s1 = 0.f, s2 = 0.f;
            #pragma unroll
            for (int ct = 0; ct < 8; ++ct) {
                float v = acc2[i][ct][r] + bu2c[ct]
                        + (float)xb[(size_t)growc * DIM + ct * 16 + l15];
                u[ct] = v; s1 += v; s2 += v * v;
            }
            #pragma unroll
            for (int off = 1; off < 16; off <<= 1) {
                s1 += __shfl_xor(s1, off);
                s2 += __shfl_xor(s2, off);
            }
            float mean = s1 * (1.f / 128.f);
            float var  = s2 * (1.f / 128.f) - mean * mean;
            float rstd = rsqrtf(var + 1e-5f);
            if (grow < N_NODES) {
                if (of32) {
                    #pragma unroll
                    for (int ct = 0; ct < 8; ++ct)
                        ((float*)out)[(size_t)grow * DIM + ct * 16 + l15] =
                            (u[ct] - mean) * rstd * gc[ct] + bc[ct];
                } else {
                    #pragma unroll
                    for (int ct = 0; ct < 8; ++ct)
                        ((bf16*)out)[(size_t)grow * DIM + ct * 16 + l15] =
                            (bf16)((u[ct] - mean) * rstd * gc[ct] + bc[ct]);
                }
            }
        }
    }
}

// ---------------------------------------------------------------------------
// CSR build: histogram -> 2-level exclusive scan -> counting-sort scatter
// ---------------------------------------------------------------------------
template<bool I64>
__device__ void hist_body(const void* ei, int* deg) {
    int e = blockIdx.x * 256 + threadIdx.x;
    if (e < N_EDGES) atomicAdd(&deg[ldi<I64>(ei, (size_t)N_EDGES + e)], 1);
}
__global__ __launch_bounds__(256) void hist_kernel(const void* ei, int* deg, const int* flags) {
    if (flags[1]) hist_body<true>(ei, deg); else hist_body<false>(ei, deg);
}

__global__ __launch_bounds__(256) void scan1_kernel(const int* __restrict__ deg,
                                                    int* __restrict__ bscan,
                                                    int* __restrict__ bsum) {
    __shared__ int s[256];
    int tid = threadIdx.x;
    int i = blockIdx.x * 256 + tid;
    int v = (i < N_NODES) ? deg[i] : 0;
    s[tid] = v;
    for (int off = 1; off < 256; off <<= 1) {
        __syncthreads();
        int t = (tid >= off) ? s[tid - off] : 0;
        __syncthreads();
        s[tid] += t;
    }
    if (i < N_NODES) bscan[i] = s[tid] - v;
    if (tid == 255) bsum[blockIdx.x] = s[255];
}

__global__ __launch_bounds__(256) void scan2_kernel(int* __restrict__ bsum) {
    __shared__ int s[256];
    int tid = threadIdx.x;
    int v = (tid < NBLK_SCAN) ? bsum[tid] : 0;
    s[tid] = v;
    for (int off = 1; off < 256; off <<= 1) {
        __syncthreads();
        int t = (tid >= off) ? s[tid - off] : 0;
        __syncthreads();
        s[tid] += t;
    }
    if (tid < NBLK_SCAN) bsum[tid] = s[tid] - v;
}

__global__ __launch_bounds__(256) void scan3_kernel(const int* __restrict__ bscan,
                                                    const int* __restrict__ bsum,
                                                    int* __restrict__ offsets) {
    int i = blockIdx.x * 256 + threadIdx.x;
    if (i < N_NODES) offsets[i] = bscan[i] + bsum[blockIdx.x];
}

template<bool I64>
__device__ void scatter_body(const void* ei, int* offsets, int* srcs) {
    int e = blockIdx.x * 256 + threadIdx.x;
    if (e < N_EDGES) {
        int d = ldi<I64>(ei, (size_t)N_EDGES + e);
        int pos = atomicAdd(&offsets[d], 1);
        srcs[pos] = ldi<I64>(ei, e);
    }
}
__global__ __launch_bounds__(256) void scatter_kernel(const void* ei, int* offsets, int* srcs,
                                                      const int* flags) {
    if (flags[1]) scatter_body<true>(ei, offsets, srcs);
    else          scatter_body<false>(ei, offsets, srcs);
}

// ---------------------------------------------------------------------------
// Per-node gather-mean, wave-per-node; 4 edges in flight x dual stream.
// ---------------------------------------------------------------------------
__device__ __forceinline__ void accum8(float* s, uint4 v) {
    v8bf b = __builtin_bit_cast(v8bf, v);
    #pragma unroll
    for (int j = 0; j < 8; ++j) s[j] += (float)b[j];
}

__global__ __launch_bounds__(256) void agg_kernel(const bf16* __restrict__ y,
                                                  const int* __restrict__ srcs,
                                                  const int* __restrict__ offsets,
                                                  const int* __restrict__ deg,
                                                  bf16* __restrict__ agg) {
    const int node = (blockIdx.x << 2) + (threadIdx.x >> 6);
    const int lane = threadIdx.x & 63;
    const int slot = lane >> 4, c16 = lane & 15;
    const int end = offsets[node];
    const int cnt = deg[node];
    const int beg = end - cnt;
    const uint4* yv = (const uint4*)y;

    float s0[8] = {}, s1[8] = {};
    int e = beg + slot;
    for (; e + 4 < end; e += 8) {
        int i0 = srcs[e], i1 = srcs[e + 4];
        uint4 v0 = yv[(size_t)i0 * 16 + c16];
        uint4 v1 = yv[(size_t)i1 * 16 + c16];
        accum8(s0, v0);
        accum8(s1, v1);
    }
    if (e < end) accum8(s0, yv[(size_t)srcs[e] * 16 + c16]);

    float inv = 1.f / (float)(cnt > 0 ? cnt : 1);
    v8bf o;
    #pragma unroll
    for (int j = 0; j < 8; ++j) {
        float v = s0[j] + s1[j];
        v += __shfl_xor(v, 16);
        v += __shfl_xor(v, 32);
        o[j] = (bf16)(v * inv);
    }
    if (slot == 0)
        ((uint4*)agg)[(size_t)node * 16 + c16] = __builtin_bit_cast(uint4, o);
}

// ---------------------------------------------------------------------------
extern "C" void kernel_launch(void* const* d_in, const int* in_sizes, int n_in,
                              void* d_out, int out_size, void* d_ws, size_t ws_size,
                              hipStream_t stream) {
    const void* x   = d_in[0];
    const void* ei  = d_in[1];

    char* ws = (char*)d_ws;
    size_t off = 0;
    auto alloc = [&](size_t bytes) {
        void* p = ws + off;
        off += (bytes + 255) & ~(size_t)255;
        return p;
    };
    bf16* y       = (bf16*)alloc((size_t)N_NODES * DIM * sizeof(bf16));  // 10.24 MB
    bf16* agg     = (bf16*)alloc((size_t)N_NODES * DIM * sizeof(bf16));  // 10.24 MB
    bf16* xb      = (bf16*)alloc((size_t)N_NODES * DIM * sizeof(bf16));  // 10.24 MB
    bf16* wp      = (bf16*)alloc((size_t)NPARAM * sizeof(bf16));         // 165 KB
    int*  deg     = (int*)alloc(N_NODES * sizeof(int));
    int*  offsets = (int*)alloc(N_NODES * sizeof(int));
    int*  bscan   = (int*)alloc(N_NODES * sizeof(int));
    int*  bsum    = (int*)alloc(1024);
    int*  srcs    = (int*)alloc((size_t)N_EDGES * sizeof(int));          // 2.56 MB
    int*  flags   = (int*)alloc(256);

    hipMemsetAsync(deg, 0, N_NODES * sizeof(int), stream);

    detect_kernel<<<1, 256, 0, stream>>>((const unsigned short*)x, (const unsigned int*)ei, flags);
    convert_params_kernel<<<(NPARAM + 255) / 256, 256, 0, stream>>>(
        d_in[2], d_in[3], d_in[4], d_in[5], d_in[6], d_in[7], d_in[8], d_in[9],
        d_in[10], d_in[11], flags, wp);
    convert_x_kernel<<<1024, 256, 0, stream>>>(x, flags, xb);

    msg_kernel<<<NBLK_GEMM, 256, 0, stream>>>(xb, wp, y);

    hist_kernel<<<(N_EDGES + 255) / 256, 256, 0, stream>>>(ei, deg, flags);
    scan1_kernel<<<NBLK_SCAN, 256, 0, stream>>>(deg, bscan, bsum);
    scan2_kernel<<<1, 256, 0, stream>>>(bsum);
    scan3_kernel<<<NBLK_SCAN, 256, 0, stream>>>(bscan, bsum, offsets);
    scatter_kernel<<<(N_EDGES + 255) / 256, 256, 0, stream>>>(ei, offsets, srcs, flags);
    agg_kernel<<<N_NODES / 4, 256, 0, stream>>>(y, srcs, offsets, deg, agg);

    update_kernel<<<NBLK_GEMM, 256, 0, stream>>>(xb, agg, wp, flags, d_out);
}